// Round 8
// baseline (472.691 us; speedup 1.0000x reference)
//
#include <hip/hip_runtime.h>

#define SEQ    1024
#define NBATCH 2048
#define INDIM  32
#define HID    12
#define G4     48          // 4*HID
#define NB     (SEQ / 4)   // float4 blocks of 4 timesteps
#define NBLK   (NB + 4)    // zx blocks incl pad blocks
#define CHUNK  16
#define NCH    (SEQ / CHUNK)

#define LOG2E 1.4426950408889634f

typedef float f32x4 __attribute__((ext_vector_type(4)));

// ---- low-latency cross-lane primitives ------------------------------------
template<int CTRL>
__device__ __forceinline__ float qbcast(float v) {
    int x = __builtin_amdgcn_update_dpp(
        0, __builtin_bit_cast(int, v), CTRL, 0xF, 0xF, true);
    return __builtin_bit_cast(float, x);
}
__device__ __forceinline__ float lanebcast(float v, int lane) {
    return __builtin_bit_cast(float,
        __builtin_amdgcn_readlane(__builtin_bit_cast(int, v), lane));
}
__device__ __forceinline__ float sig_part(float zs) {   // rcp(1 + exp2(zs))
    return __builtin_amdgcn_rcpf(1.0f + __builtin_amdgcn_exp2f(zs));
}

// 12-FMA dot, 6 accumulators: depth = 2 fma + 3 add.
#define DOT12(acc_init, W, H, OUT) { \
    float d0 = (acc_init), d1 = 0.f, d2 = 0.f, d3 = 0.f, d4 = 0.f, d5 = 0.f; \
    d0 = fmaf(H[0], W[0], d0); d1 = fmaf(H[1],  W[1],  d1); d2 = fmaf(H[2],  W[2],  d2); \
    d3 = fmaf(H[3], W[3], d3); d4 = fmaf(H[4],  W[4],  d4); d5 = fmaf(H[5],  W[5],  d5); \
    d0 = fmaf(H[6], W[6], d0); d1 = fmaf(H[7],  W[7],  d1); d2 = fmaf(H[8],  W[8],  d2); \
    d3 = fmaf(H[9], W[9], d3); d4 = fmaf(H[10], W[10], d4); d5 = fmaf(H[11], W[11], d5); \
    OUT = ((d0 + d1) + (d2 + d3)) + (d4 + d5); \
}

// ---------------------------------------------------------------------------
// Kernel 0: clock probe. 150,000 DEPENDENT v_fma_f32 in one wave.
// dep-fma latency = 4 cyc (HW-verified) -> dur_us = 600k cyc / SCLK.
// 250 us => 2.4 GHz ; ~500 us => 1.2 GHz. Also acts as a DVFS warmer.
// ---------------------------------------------------------------------------
__global__ __launch_bounds__(64) void clk_probe(float* __restrict__ sink) {
    float x = 1.0f + (float)threadIdx.x * 1e-7f;
    for (int i = 0; i < 9375; ++i) {          // 9375 * 16 = 150,000
        #pragma unroll
        for (int u = 0; u < 16; ++u)
            x = fmaf(x, 0.99999988f, 1e-7f);  // dependent chain
    }
    if (threadIdx.x == 0) sink[0] = x;
}

// ---------------------------------------------------------------------------
// Kernel 1: layer-0 x-part, bias folded, PRE-SCALED by cexp(g):
//   zx[b*192 + j*4 + q] = cexp(g) * (b[r] + Wih0[r,:]·X[t,2047,:]),
//   t = 4b+q, j = 4*k+g, r = g*12+k.  Blocks b in [0,NBLK); t>=SEQ zeroed.
// ---------------------------------------------------------------------------
__global__ __launch_bounds__(256) void lstm_pre(
    const float* __restrict__ X,
    const float* __restrict__ Wih0,
    const float* __restrict__ bih0,
    const float* __restrict__ bhh0,
    float* __restrict__ zx)
{
    int idx = blockIdx.x * blockDim.x + threadIdx.x;
    if (idx >= NBLK * 192) return;
    int b   = idx / 192;
    int rem = idx - b * 192;
    int j   = rem >> 2;
    int q   = rem & 3;
    int t   = 4 * b + q;
    if (t >= SEQ) { zx[idx] = 0.0f; return; }
    int g = j & 3, k = j >> 2;
    int r = g * HID + k;
    const float cexpg = (g == 2) ? (-2.0f * LOG2E) : (-LOG2E);
    const float* x = X + (size_t)t * NBATCH * INDIM + (size_t)(NBATCH - 1) * INDIM;
    const float* w = Wih0 + r * INDIM;
    float za = bih0[r] + bhh0[r], zb = 0.0f;
    #pragma unroll
    for (int kk = 0; kk < INDIM; kk += 2) {
        za = fmaf(w[kk],     x[kk],     za);
        zb = fmaf(w[kk + 1], x[kk + 1], zb);
    }
    zx[idx] = (za + zb) * cexpg;
}

// ---------------------------------------------------------------------------
// Kernel 2: two-wave barrier-lockstep pipeline (v3 + chain surgery).
// ---------------------------------------------------------------------------
__global__ __launch_bounds__(128) void lstm_seq3(
    const f32x4* __restrict__ zx4,     // [NBLK][48] f32x4, pre-scaled
    float* __restrict__ hbuf,          // [SEQ][12] h1 per step
    const float* __restrict__ Whh0,
    const float* __restrict__ Wih1,
    const float* __restrict__ Whh1,
    const float* __restrict__ bih1,
    const float* __restrict__ bhh1)
{
    __shared__ float ylds[64 * 64];    // 64-step ring x 64 cols (48 used)

    const int tid  = threadIdx.x;
    const int wavei = tid >> 6;
    const int lane = tid & 63;
    const int jj = (lane < G4) ? lane : 0;
    const int g  = jj & 3;                 // gate: 0=i 1=f 2=g 3=o
    const int k  = jj >> 2;                // hidden unit
    const int r  = g * HID + k;            // weight row
    const float cexp = (g == 2) ? (-2.0f * LOG2E) : (-LOG2E);
    const float TSA = -4.0f * LOG2E;
    const float TSB =  2.0f * LOG2E;

    float wh0a[HID], wi1a[HID];      // A weights (scaled)
    float h0s[HID];  float cs0 = 0.f;
    f32x4 zbE[4], zbO[4];
    float b1s = 0.f;
    float wh1b[HID];                 // B weights (scaled)
    float h1s[HID];  float cs1 = 0.f;
    float yv0 = 0.f, yv1 = 0.f, yv2 = 0.f, yv3 = 0.f;

    if (wavei == 0) {
        #pragma unroll
        for (int kk = 0; kk < HID; ++kk) {
            wh0a[kk] = Whh0[r * HID + kk] * cexp;
            wi1a[kk] = Wih1[r * HID + kk] * cexp;
            h0s[kk] = 0.f;
        }
        b1s = (bih1[r] + bhh1[r]) * cexp;
        #pragma unroll
        for (int bb = 0; bb < 4; ++bb) zbE[bb] = zx4[bb * G4 + jj];
    } else {
        #pragma unroll
        for (int kk = 0; kk < HID; ++kk) {
            wh1b[kk] = Whh1[r * HID + kk] * cexp;
            h1s[kk] = 0.f;
        }
    }
    __syncthreads();

// gate combine: m1,m2 parallel depth-1, igs depth-2, cs depth-3 from rr
#define GATECOMB(rr, cs) { \
    float ai = qbcast<0x00>(rr), af = qbcast<0x55>(rr); \
    float ag = qbcast<0xAA>(rr); \
    float m1 = ai * ag; \
    float m2 = TSB * ai; \
    cs = fmaf(af, cs, fmaf(TSA, m1, m2)); \
}

#define STEPA(zs, t) { \
    float z0v; DOT12((zs), wh0a, h0s, z0v) \
    float rr = sig_part(z0v); \
    float ao = qbcast<0xFF>(rr); \
    GATECOMB(rr, cs0) \
    float rt = sig_part(cs0); \
    float h0 = fmaf(ao + ao, rt, -ao); \
    h0s[0] = lanebcast(h0, 0);  h0s[1] = lanebcast(h0, 4);  h0s[2]  = lanebcast(h0, 8); \
    h0s[3] = lanebcast(h0, 12); h0s[4] = lanebcast(h0, 16); h0s[5]  = lanebcast(h0, 20); \
    h0s[6] = lanebcast(h0, 24); h0s[7] = lanebcast(h0, 28); h0s[8]  = lanebcast(h0, 32); \
    h0s[9] = lanebcast(h0, 36); h0s[10] = lanebcast(h0, 40); h0s[11] = lanebcast(h0, 44); \
    float yo; DOT12(b1s, wi1a, h0s, yo) \
    ylds[(((t) & 63) << 6) + lane] = yo; \
}

#define AITER(cur, nxt, ci) { \
    int cb = 4 * ((ci) + 1); \
    nxt[0] = zx4[(cb + 0) * G4 + jj]; \
    nxt[1] = zx4[(cb + 1) * G4 + jj]; \
    nxt[2] = zx4[(cb + 2) * G4 + jj]; \
    nxt[3] = zx4[(cb + 3) * G4 + jj]; \
    int tA = CHUNK * (ci); \
    STEPA(cur[0].x, tA + 0)  STEPA(cur[0].y, tA + 1)  STEPA(cur[0].z, tA + 2)  STEPA(cur[0].w, tA + 3)  \
    STEPA(cur[1].x, tA + 4)  STEPA(cur[1].y, tA + 5)  STEPA(cur[1].z, tA + 6)  STEPA(cur[1].w, tA + 7)  \
    STEPA(cur[2].x, tA + 8)  STEPA(cur[2].y, tA + 9)  STEPA(cur[2].z, tA + 10) STEPA(cur[2].w, tA + 11) \
    STEPA(cur[3].x, tA + 12) STEPA(cur[3].y, tA + 13) STEPA(cur[3].z, tA + 14) STEPA(cur[3].w, tA + 15) \
}

#define STEPB(yin, t) { \
    float z1v; DOT12((yin), wh1b, h1s, z1v) \
    float rr = sig_part(z1v); \
    float ao = qbcast<0xFF>(rr); \
    GATECOMB(rr, cs1) \
    float rt = sig_part(cs1); \
    float h1 = fmaf(ao + ao, rt, -ao); \
    if (lane < G4 && g == 0) hbuf[(t) * HID + k] = h1; \
    h1s[0] = lanebcast(h1, 0);  h1s[1] = lanebcast(h1, 4);  h1s[2]  = lanebcast(h1, 8); \
    h1s[3] = lanebcast(h1, 12); h1s[4] = lanebcast(h1, 16); h1s[5]  = lanebcast(h1, 20); \
    h1s[6] = lanebcast(h1, 24); h1s[7] = lanebcast(h1, 28); h1s[8]  = lanebcast(h1, 32); \
    h1s[9] = lanebcast(h1, 36); h1s[10] = lanebcast(h1, 40); h1s[11] = lanebcast(h1, 44); \
}

#define BGRP(t0) { \
    int rb = ((((t0) + 4) & 63) << 6) + jj; \
    float n0 = ylds[rb], n1 = ylds[rb + 64], n2 = ylds[rb + 128], n3 = ylds[rb + 192]; \
    STEPB(yv0, (t0))     STEPB(yv1, (t0) + 1) \
    STEPB(yv2, (t0) + 2) STEPB(yv3, (t0) + 3) \
    yv0 = n0; yv1 = n1; yv2 = n2; yv3 = n3; \
}

    for (int i = 0; i < NCH + 2; ++i) {
        if (wavei == 0) {
            if (i < NCH) {
                if ((i & 1) == 0) { AITER(zbE, zbO, i) }
                else              { AITER(zbO, zbE, i) }
            }
        } else {
            if (i >= 2) {
                int t0 = (i - 2) * CHUNK;
                if (i == 2) {
                    yv0 = ylds[jj];       yv1 = ylds[64 + jj];
                    yv2 = ylds[128 + jj]; yv3 = ylds[192 + jj];
                }
                BGRP(t0) BGRP(t0 + 4) BGRP(t0 + 8) BGRP(t0 + 12)
            }
        }
        __syncthreads();
    }
#undef STEPA
#undef AITER
#undef STEPB
#undef BGRP
#undef GATECOMB
}

// ---------------------------------------------------------------------------
// Kernel 3: FC head, parallel over t: out[t] = bfc + Wfc . h1(t)
// ---------------------------------------------------------------------------
__global__ __launch_bounds__(256) void fc_head(
    const float* __restrict__ hbuf,
    const float* __restrict__ Wfc,
    const float* __restrict__ bfc,
    float* __restrict__ out)
{
    int t = blockIdx.x * blockDim.x + threadIdx.x;
    if (t >= SEQ) return;
    float o = bfc[0];
    const float* h = hbuf + t * HID;
    #pragma unroll
    for (int kk = 0; kk < HID; ++kk) o = fmaf(Wfc[kk], h[kk], o);
    out[t] = o;
}

// ---------------------------------------------------------------------------
// Fallback (no workspace): single-wave full computation, inline FC.
// ---------------------------------------------------------------------------
__global__ __launch_bounds__(64) void lstm_seq_fb(
    const float* __restrict__ X,
    const float* __restrict__ Wih0,
    const float* __restrict__ bih0,
    const float* __restrict__ bhh0,
    const float* __restrict__ Whh0,
    const float* __restrict__ Wih1,
    const float* __restrict__ Whh1,
    const float* __restrict__ bih1,
    const float* __restrict__ bhh1,
    const float* __restrict__ Wfc,
    const float* __restrict__ bfc,
    float* __restrict__ out)
{
    const int j  = threadIdx.x;
    const int jj = (j < G4) ? j : 0;
    const int g  = jj & 3;
    const int k  = jj >> 2;
    const int r  = g * HID + k;
    const float cexp = (g == 2) ? (-2.0f * LOG2E) : (-LOG2E);
    const float TSA = -4.0f * LOG2E;
    const float TSB =  2.0f * LOG2E;

    float whh0[HID], wih1[HID], whh1[HID], wih0[INDIM], wfc[HID];
    #pragma unroll
    for (int kk = 0; kk < HID; ++kk) {
        whh0[kk] = Whh0[r * HID + kk] * cexp;
        wih1[kk] = Wih1[r * HID + kk] * cexp;
        whh1[kk] = Whh1[r * HID + kk] * cexp;
        wfc[kk]  = Wfc[kk];
    }
    #pragma unroll
    for (int kk = 0; kk < INDIM; ++kk) wih0[kk] = Wih0[r * INDIM + kk] * cexp;
    const float b0 = (bih0[r] + bhh0[r]) * cexp;
    const float b1 = (bih1[r] + bhh1[r]) * cexp;
    const float bias_fc = bfc[0];

    float h0v[HID], h1v[HID];
    #pragma unroll
    for (int kk = 0; kk < HID; ++kk) { h0v[kk] = 0.0f; h1v[kk] = 0.0f; }
    float cs0 = 0.0f, cs1 = 0.0f;

    for (int t = 0; t < SEQ; ++t) {
        const float* x = X + (size_t)t * NBATCH * INDIM
                           + (size_t)(NBATCH - 1) * INDIM;
        float z0 = b0;
        #pragma unroll
        for (int kk = 0; kk < INDIM; ++kk) z0 = fmaf(wih0[kk], x[kk], z0);
        #pragma unroll
        for (int kk = 0; kk < HID; ++kk) z0 = fmaf(whh0[kk], h0v[kk], z0);
        float rr = sig_part(z0);
        float ai = qbcast<0x00>(rr), af = qbcast<0x55>(rr);
        float ag = qbcast<0xAA>(rr), ao = qbcast<0xFF>(rr);
        cs0 = fmaf(af, cs0, ai * fmaf(TSA, ag, TSB));
        float rt = sig_part(cs0);
        float h0 = fmaf(ao + ao, rt, -ao);
        #pragma unroll
        for (int kk = 0; kk < HID; ++kk) h0v[kk] = lanebcast(h0, 4 * kk);

        float z1 = b1;
        #pragma unroll
        for (int kk = 0; kk < HID; ++kk) {
            z1 = fmaf(wih1[kk], h0v[kk], z1);
            z1 = fmaf(whh1[kk], h1v[kk], z1);
        }
        rr = sig_part(z1);
        ai = qbcast<0x00>(rr); af = qbcast<0x55>(rr);
        ag = qbcast<0xAA>(rr); ao = qbcast<0xFF>(rr);
        cs1 = fmaf(af, cs1, ai * fmaf(TSA, ag, TSB));
        rt = sig_part(cs1);
        float h1 = fmaf(ao + ao, rt, -ao);
        #pragma unroll
        for (int kk = 0; kk < HID; ++kk) h1v[kk] = lanebcast(h1, 4 * kk);

        float o = bias_fc;
        #pragma unroll
        for (int kk = 0; kk < HID; ++kk) o = fmaf(wfc[kk], h1v[kk], o);
        if (j == 0) out[t] = o;
    }
}

extern "C" void kernel_launch(void* const* d_in, const int* in_sizes, int n_in,
                              void* d_out, int out_size, void* d_ws, size_t ws_size,
                              hipStream_t stream) {
    const float* X    = (const float*)d_in[0];
    const float* Wih0 = (const float*)d_in[1];
    const float* Whh0 = (const float*)d_in[2];
    const float* bih0 = (const float*)d_in[3];
    const float* bhh0 = (const float*)d_in[4];
    const float* Wih1 = (const float*)d_in[5];
    const float* Whh1 = (const float*)d_in[6];
    const float* bih1 = (const float*)d_in[7];
    const float* bhh1 = (const float*)d_in[8];
    const float* Wfc  = (const float*)d_in[9];
    const float* bfc  = (const float*)d_in[10];
    float* out = (float*)d_out;

    const size_t zx_floats = (size_t)NBLK * 192;
    const size_t need = (zx_floats + (size_t)SEQ * HID + 1) * sizeof(float);
    if (ws_size >= need) {
        float* zbuf = (float*)d_ws;
        float* hbuf = zbuf + zx_floats;
        float* sink = hbuf + (size_t)SEQ * HID;
        clk_probe<<<1, 64, 0, stream>>>(sink);
        lstm_pre<<<(NBLK * 192 + 255) / 256, 256, 0, stream>>>(
            X, Wih0, bih0, bhh0, zbuf);
        lstm_seq3<<<1, 128, 0, stream>>>(
            (const f32x4*)zbuf, hbuf, Whh0, Wih1, Whh1, bih1, bhh1);
        fc_head<<<(SEQ + 255) / 256, 256, 0, stream>>>(hbuf, Wfc, bfc, out);
    } else {
        lstm_seq_fb<<<1, 64, 0, stream>>>(
            X, Wih0, bih0, bhh0, Whh0,
            Wih1, Whh1, bih1, bhh1, Wfc, bfc, out);
    }
}

// Round 9
// 145.153 us; speedup vs baseline: 3.2565x; 3.2565x over previous
//
#include <hip/hip_runtime.h>

#define SEQ    1024
#define NBATCH 2048
#define INDIM  32
#define HID    12
#define G4     48          // 4*HID
#define NB     (SEQ / 4)   // float4 blocks of 4 timesteps
#define NBLK   (NB + 4)    // zx blocks incl pad blocks
#define CHUNK  16
#define NCH    (SEQ / CHUNK)

#define LOG2E 1.4426950408889634f

typedef float f32x4 __attribute__((ext_vector_type(4)));

// ---- low-latency cross-lane primitives ------------------------------------
template<int CTRL>
__device__ __forceinline__ float qbcast(float v) {
    int x = __builtin_amdgcn_update_dpp(
        0, __builtin_bit_cast(int, v), CTRL, 0xF, 0xF, true);
    return __builtin_bit_cast(float, x);
}
__device__ __forceinline__ float lanebcast(float v, int lane) {
    return __builtin_bit_cast(float,
        __builtin_amdgcn_readlane(__builtin_bit_cast(int, v), lane));
}
__device__ __forceinline__ float sig_part(float zs) {   // rcp(1 + exp2(zs))
    return __builtin_amdgcn_rcpf(1.0f + __builtin_amdgcn_exp2f(zs));
}

// 12-FMA dot, 6 accumulators: depth = 2 fma + 3 add. H = 12 scalars (SGPR).
#define DOT12(acc_init, W, H, OUT) { \
    float d0 = (acc_init), d1 = 0.f, d2 = 0.f, d3 = 0.f, d4 = 0.f, d5 = 0.f; \
    d0 = fmaf(H[0], W[0], d0); d1 = fmaf(H[1],  W[1],  d1); d2 = fmaf(H[2],  W[2],  d2); \
    d3 = fmaf(H[3], W[3], d3); d4 = fmaf(H[4],  W[4],  d4); d5 = fmaf(H[5],  W[5],  d5); \
    d0 = fmaf(H[6], W[6], d0); d1 = fmaf(H[7],  W[7],  d1); d2 = fmaf(H[8],  W[8],  d2); \
    d3 = fmaf(H[9], W[9], d3); d4 = fmaf(H[10], W[10], d4); d5 = fmaf(H[11], W[11], d5); \
    OUT = ((d0 + d1) + (d2 + d3)) + (d4 + d5); \
}

// 12-FMA dot, H = three f32x4 (VGPR, LDS-broadcast values)
#define DOT12V(acc_init, W, H0, H1, H2, OUT) { \
    float d0 = (acc_init), d1 = 0.f, d2 = 0.f, d3 = 0.f, d4 = 0.f, d5 = 0.f; \
    d0 = fmaf(H0.x, W[0], d0); d1 = fmaf(H0.y, W[1],  d1); d2 = fmaf(H0.z, W[2],  d2); \
    d3 = fmaf(H0.w, W[3], d3); d4 = fmaf(H1.x, W[4],  d4); d5 = fmaf(H1.y, W[5],  d5); \
    d0 = fmaf(H1.z, W[6], d0); d1 = fmaf(H1.w, W[7],  d1); d2 = fmaf(H2.x, W[8],  d2); \
    d3 = fmaf(H2.y, W[9], d3); d4 = fmaf(H2.z, W[10], d4); d5 = fmaf(H2.w, W[11], d5); \
    OUT = ((d0 + d1) + (d2 + d3)) + (d4 + d5); \
}

// ---------------------------------------------------------------------------
// Kernel 1: layer-0 x-part, bias folded, PRE-SCALED by cexp(g):
//   zx[b*192 + j*4 + q] = cexp(g) * (b[r] + Wih0[r,:]·X[t,2047,:]),
//   t = 4b+q, j = 4*k+g, r = g*12+k.  Blocks b in [0,NBLK); t>=SEQ zeroed.
// ---------------------------------------------------------------------------
__global__ __launch_bounds__(256) void lstm_pre(
    const float* __restrict__ X,
    const float* __restrict__ Wih0,
    const float* __restrict__ bih0,
    const float* __restrict__ bhh0,
    float* __restrict__ zx)
{
    int idx = blockIdx.x * blockDim.x + threadIdx.x;
    if (idx >= NBLK * 192) return;
    int b   = idx / 192;
    int rem = idx - b * 192;
    int j   = rem >> 2;
    int q   = rem & 3;
    int t   = 4 * b + q;
    if (t >= SEQ) { zx[idx] = 0.0f; return; }
    int g = j & 3, k = j >> 2;
    int r = g * HID + k;
    const float cexpg = (g == 2) ? (-2.0f * LOG2E) : (-LOG2E);
    const float* x = X + (size_t)t * NBATCH * INDIM + (size_t)(NBATCH - 1) * INDIM;
    const float* w = Wih0 + r * INDIM;
    float za = bih0[r] + bhh0[r], zb = 0.0f;
    #pragma unroll
    for (int kk = 0; kk < INDIM; kk += 2) {
        za = fmaf(w[kk],     x[kk],     za);
        zb = fmaf(w[kk + 1], x[kk + 1], zb);
    }
    zx[idx] = (za + zb) * cexpg;
}

// ---------------------------------------------------------------------------
// Kernel 2: FOUR-wave barrier-lockstep pipeline (one workgroup, 256 thr).
//   wave 0 (A): layer-0 recurrence; h0 row -> h0r ring.     chunk i
//   wave 1 (C): y(t)=cexp*(b1+Wih1*h0) from h0r -> yr ring. chunk i-1
//   wave 2 (B): layer-1 recurrence from yr; h1 -> h1r ring. chunk i-3
//   wave 3 (D): FC head from h1r -> out.                    chunk i-4
// One __syncthreads per iteration; ring depth 64 > max lag window.
// ---------------------------------------------------------------------------
__global__ __launch_bounds__(256) void lstm_seq4(
    const f32x4* __restrict__ zx4,     // [NBLK][48] f32x4, pre-scaled
    const float* __restrict__ Whh0,
    const float* __restrict__ Wih1,
    const float* __restrict__ Whh1,
    const float* __restrict__ bih1,
    const float* __restrict__ bhh1,
    const float* __restrict__ Wfc,
    const float* __restrict__ bfc,
    float* __restrict__ out)
{
    __shared__ alignas(16) float h0r[64 * 16];   // 4 KB ring: h0 rows
    __shared__ alignas(16) float h1r[64 * 16];   // 4 KB ring: h1 rows
    __shared__ float yr[64 * 64];                // 16 KB ring: y rows (48 used)

    const int tid  = threadIdx.x;
    const int wavei = tid >> 6;
    const int lane = tid & 63;
    const int jj = (lane < G4) ? lane : 0;
    const int g  = jj & 3;                 // gate: 0=i 1=f 2=g 3=o
    const int k  = jj >> 2;                // hidden unit
    const int r  = g * HID + k;            // weight row
    const float cexp = (g == 2) ? (-2.0f * LOG2E) : (-LOG2E);
    const float TSA = -4.0f * LOG2E;
    const float TSB =  2.0f * LOG2E;

    // per-wave state (register-allocated per path)
    float wh0a[HID];  float h0s[HID];  float cs0 = 0.f;   // A
    f32x4 zbE[4], zbO[4];                                  // A
    float wi1a[HID];  float b1s = 0.f;                     // C
    float wh1b[HID];  float h1s[HID];  float cs1 = 0.f;    // B
    float yv0 = 0.f, yv1 = 0.f, yv2 = 0.f, yv3 = 0.f;      // B
    float wfcv[HID];  float bfcv = 0.f;                    // D

    if (wavei == 0) {
        #pragma unroll
        for (int kk = 0; kk < HID; ++kk) {
            wh0a[kk] = Whh0[r * HID + kk] * cexp;
            h0s[kk] = 0.f;
        }
        #pragma unroll
        for (int bb = 0; bb < 4; ++bb) zbE[bb] = zx4[bb * G4 + jj];
    } else if (wavei == 1) {
        #pragma unroll
        for (int kk = 0; kk < HID; ++kk)
            wi1a[kk] = Wih1[r * HID + kk] * cexp;
        b1s = (bih1[r] + bhh1[r]) * cexp;
    } else if (wavei == 2) {
        #pragma unroll
        for (int kk = 0; kk < HID; ++kk) {
            wh1b[kk] = Whh1[r * HID + kk] * cexp;
            h1s[kk] = 0.f;
        }
    } else {
        #pragma unroll
        for (int kk = 0; kk < HID; ++kk) wfcv[kk] = Wfc[kk];
        bfcv = bfc[0];
    }
    __syncthreads();

// gate combine from raw sigmoid rr: cs = af*cs + (TSA*(ai*ag) + TSB*ai)
#define GATECOMB(rr, cs) { \
    float ai = qbcast<0x00>(rr), af = qbcast<0x55>(rr); \
    float ag = qbcast<0xAA>(rr); \
    float m1 = ai * ag; \
    float m2 = TSB * ai; \
    cs = fmaf(af, cs, fmaf(TSA, m1, m2)); \
}

#define STEPA(zs, t) { \
    float z0v; DOT12((zs), wh0a, h0s, z0v) \
    float rr = sig_part(z0v); \
    float ao = qbcast<0xFF>(rr); \
    GATECOMB(rr, cs0) \
    float rt = sig_part(cs0); \
    float h0 = fmaf(ao + ao, rt, -ao); \
    if (lane < G4 && g == 0) h0r[((t) & 63) * 16 + k] = h0; \
    h0s[0] = lanebcast(h0, 0);  h0s[1] = lanebcast(h0, 4);  h0s[2]  = lanebcast(h0, 8); \
    h0s[3] = lanebcast(h0, 12); h0s[4] = lanebcast(h0, 16); h0s[5]  = lanebcast(h0, 20); \
    h0s[6] = lanebcast(h0, 24); h0s[7] = lanebcast(h0, 28); h0s[8]  = lanebcast(h0, 32); \
    h0s[9] = lanebcast(h0, 36); h0s[10] = lanebcast(h0, 40); h0s[11] = lanebcast(h0, 44); \
}

#define AITER(cur, nxt, ci) { \
    int cb = 4 * ((ci) + 1); \
    nxt[0] = zx4[(cb + 0) * G4 + jj]; \
    nxt[1] = zx4[(cb + 1) * G4 + jj]; \
    nxt[2] = zx4[(cb + 2) * G4 + jj]; \
    nxt[3] = zx4[(cb + 3) * G4 + jj]; \
    int tA = CHUNK * (ci); \
    STEPA(cur[0].x, tA + 0)  STEPA(cur[0].y, tA + 1)  STEPA(cur[0].z, tA + 2)  STEPA(cur[0].w, tA + 3)  \
    STEPA(cur[1].x, tA + 4)  STEPA(cur[1].y, tA + 5)  STEPA(cur[1].z, tA + 6)  STEPA(cur[1].w, tA + 7)  \
    STEPA(cur[2].x, tA + 8)  STEPA(cur[2].y, tA + 9)  STEPA(cur[2].z, tA + 10) STEPA(cur[2].w, tA + 11) \
    STEPA(cur[3].x, tA + 12) STEPA(cur[3].y, tA + 13) STEPA(cur[3].z, tA + 14) STEPA(cur[3].w, tA + 15) \
}

#define CSTEP(t) { \
    const f32x4 ha = *(const f32x4*)&h0r[((t) & 63) * 16 + 0]; \
    const f32x4 hb = *(const f32x4*)&h0r[((t) & 63) * 16 + 4]; \
    const f32x4 hc = *(const f32x4*)&h0r[((t) & 63) * 16 + 8]; \
    float yo; DOT12V(b1s, wi1a, ha, hb, hc, yo) \
    yr[((t) & 63) * 64 + lane] = yo; \
}

#define STEPB(yin, t) { \
    float z1v; DOT12((yin), wh1b, h1s, z1v) \
    float rr = sig_part(z1v); \
    float ao = qbcast<0xFF>(rr); \
    GATECOMB(rr, cs1) \
    float rt = sig_part(cs1); \
    float h1 = fmaf(ao + ao, rt, -ao); \
    if (lane < G4 && g == 0) h1r[((t) & 63) * 16 + k] = h1; \
    h1s[0] = lanebcast(h1, 0);  h1s[1] = lanebcast(h1, 4);  h1s[2]  = lanebcast(h1, 8); \
    h1s[3] = lanebcast(h1, 12); h1s[4] = lanebcast(h1, 16); h1s[5]  = lanebcast(h1, 20); \
    h1s[6] = lanebcast(h1, 24); h1s[7] = lanebcast(h1, 28); h1s[8]  = lanebcast(h1, 32); \
    h1s[9] = lanebcast(h1, 36); h1s[10] = lanebcast(h1, 40); h1s[11] = lanebcast(h1, 44); \
}

#define BGRP(t0) { \
    int rb = ((((t0) + 4) & 63) << 6) + jj; \
    float n0 = yr[rb], n1 = yr[rb + 64], n2 = yr[rb + 128], n3 = yr[rb + 192]; \
    STEPB(yv0, (t0))     STEPB(yv1, (t0) + 1) \
    STEPB(yv2, (t0) + 2) STEPB(yv3, (t0) + 3) \
    yv0 = n0; yv1 = n1; yv2 = n2; yv3 = n3; \
}

    for (int i = 0; i < NCH + 4; ++i) {
        if (wavei == 0) {
            // ---- A: layer-0, chunk i ----
            if (i < NCH) {
                if ((i & 1) == 0) { AITER(zbE, zbO, i) }
                else              { AITER(zbO, zbE, i) }
            }
        } else if (wavei == 1) {
            // ---- C: y-precompute, chunk i-1 ----
            if (i >= 1 && i <= NCH) {
                int tc = (i - 1) * CHUNK;
                CSTEP(tc + 0)  CSTEP(tc + 1)  CSTEP(tc + 2)  CSTEP(tc + 3)
                CSTEP(tc + 4)  CSTEP(tc + 5)  CSTEP(tc + 6)  CSTEP(tc + 7)
                CSTEP(tc + 8)  CSTEP(tc + 9)  CSTEP(tc + 10) CSTEP(tc + 11)
                CSTEP(tc + 12) CSTEP(tc + 13) CSTEP(tc + 14) CSTEP(tc + 15)
            }
        } else if (wavei == 2) {
            // ---- B: layer-1, chunk i-3 ----
            if (i >= 3 && i < NCH + 3) {
                int t0 = (i - 3) * CHUNK;
                if (i == 3) {
                    yv0 = yr[jj];       yv1 = yr[64 + jj];
                    yv2 = yr[128 + jj]; yv3 = yr[192 + jj];
                }
                BGRP(t0) BGRP(t0 + 4) BGRP(t0 + 8) BGRP(t0 + 12)
            }
        } else {
            // ---- D: FC head, chunk i-4 ----
            if (i >= 4 && lane < CHUNK) {
                int t = (i - 4) * CHUNK + lane;
                float o = bfcv;
                #pragma unroll
                for (int kk = 0; kk < HID; ++kk)
                    o = fmaf(wfcv[kk], h1r[(t & 63) * 16 + kk], o);
                out[t] = o;
            }
        }
        __syncthreads();
    }
#undef STEPA
#undef AITER
#undef CSTEP
#undef STEPB
#undef BGRP
#undef GATECOMB
}

// ---------------------------------------------------------------------------
// Fallback (no workspace): single-wave full computation, inline FC.
// ---------------------------------------------------------------------------
__global__ __launch_bounds__(64) void lstm_seq_fb(
    const float* __restrict__ X,
    const float* __restrict__ Wih0,
    const float* __restrict__ bih0,
    const float* __restrict__ bhh0,
    const float* __restrict__ Whh0,
    const float* __restrict__ Wih1,
    const float* __restrict__ Whh1,
    const float* __restrict__ bih1,
    const float* __restrict__ bhh1,
    const float* __restrict__ Wfc,
    const float* __restrict__ bfc,
    float* __restrict__ out)
{
    const int j  = threadIdx.x;
    const int jj = (j < G4) ? j : 0;
    const int g  = jj & 3;
    const int k  = jj >> 2;
    const int r  = g * HID + k;
    const float cexp = (g == 2) ? (-2.0f * LOG2E) : (-LOG2E);
    const float TSA = -4.0f * LOG2E;
    const float TSB =  2.0f * LOG2E;

    float whh0[HID], wih1[HID], whh1[HID], wih0[INDIM], wfc[HID];
    #pragma unroll
    for (int kk = 0; kk < HID; ++kk) {
        whh0[kk] = Whh0[r * HID + kk] * cexp;
        wih1[kk] = Wih1[r * HID + kk] * cexp;
        whh1[kk] = Whh1[r * HID + kk] * cexp;
        wfc[kk]  = Wfc[kk];
    }
    #pragma unroll
    for (int kk = 0; kk < INDIM; ++kk) wih0[kk] = Wih0[r * INDIM + kk] * cexp;
    const float b0 = (bih0[r] + bhh0[r]) * cexp;
    const float b1 = (bih1[r] + bhh1[r]) * cexp;
    const float bias_fc = bfc[0];

    float h0v[HID], h1v[HID];
    #pragma unroll
    for (int kk = 0; kk < HID; ++kk) { h0v[kk] = 0.0f; h1v[kk] = 0.0f; }
    float cs0 = 0.0f, cs1 = 0.0f;

    for (int t = 0; t < SEQ; ++t) {
        const float* x = X + (size_t)t * NBATCH * INDIM
                           + (size_t)(NBATCH - 1) * INDIM;
        float z0 = b0;
        #pragma unroll
        for (int kk = 0; kk < INDIM; ++kk) z0 = fmaf(wih0[kk], x[kk], z0);
        #pragma unroll
        for (int kk = 0; kk < HID; ++kk) z0 = fmaf(whh0[kk], h0v[kk], z0);
        float rr = sig_part(z0);
        float ai = qbcast<0x00>(rr), af = qbcast<0x55>(rr);
        float ag = qbcast<0xAA>(rr), ao = qbcast<0xFF>(rr);
        cs0 = fmaf(af, cs0, ai * fmaf(TSA, ag, TSB));
        float rt = sig_part(cs0);
        float h0 = fmaf(ao + ao, rt, -ao);
        #pragma unroll
        for (int kk = 0; kk < HID; ++kk) h0v[kk] = lanebcast(h0, 4 * kk);

        float z1 = b1;
        #pragma unroll
        for (int kk = 0; kk < HID; ++kk) {
            z1 = fmaf(wih1[kk], h0v[kk], z1);
            z1 = fmaf(whh1[kk], h1v[kk], z1);
        }
        rr = sig_part(z1);
        ai = qbcast<0x00>(rr); af = qbcast<0x55>(rr);
        ag = qbcast<0xAA>(rr); ao = qbcast<0xFF>(rr);
        cs1 = fmaf(af, cs1, ai * fmaf(TSA, ag, TSB));
        rt = sig_part(cs1);
        float h1 = fmaf(ao + ao, rt, -ao);
        #pragma unroll
        for (int kk = 0; kk < HID; ++kk) h1v[kk] = lanebcast(h1, 4 * kk);

        float o = bias_fc;
        #pragma unroll
        for (int kk = 0; kk < HID; ++kk) o = fmaf(wfc[kk], h1v[kk], o);
        if (j == 0) out[t] = o;
    }
}

extern "C" void kernel_launch(void* const* d_in, const int* in_sizes, int n_in,
                              void* d_out, int out_size, void* d_ws, size_t ws_size,
                              hipStream_t stream) {
    const float* X    = (const float*)d_in[0];
    const float* Wih0 = (const float*)d_in[1];
    const float* Whh0 = (const float*)d_in[2];
    const float* bih0 = (const float*)d_in[3];
    const float* bhh0 = (const float*)d_in[4];
    const float* Wih1 = (const float*)d_in[5];
    const float* Whh1 = (const float*)d_in[6];
    const float* bih1 = (const float*)d_in[7];
    const float* bhh1 = (const float*)d_in[8];
    const float* Wfc  = (const float*)d_in[9];
    const float* bfc  = (const float*)d_in[10];
    float* out = (float*)d_out;

    const size_t need = (size_t)NBLK * 192 * sizeof(float);
    if (ws_size >= need) {
        float* zbuf = (float*)d_ws;
        lstm_pre<<<(NBLK * 192 + 255) / 256, 256, 0, stream>>>(
            X, Wih0, bih0, bhh0, zbuf);
        lstm_seq4<<<1, 256, 0, stream>>>(
            (const f32x4*)zbuf, Whh0, Wih1, Whh1, bih1, bhh1, Wfc, bfc, out);
    } else {
        lstm_seq_fb<<<1, 64, 0, stream>>>(
            X, Wih0, bih0, bhh0, Whh0,
            Wih1, Whh1, bih1, bhh1, Wfc, bfc, out);
    }
}

// Round 10
// 143.064 us; speedup vs baseline: 3.3041x; 1.0146x over previous
//
#include <hip/hip_runtime.h>

#define SEQ    1024
#define NBATCH 2048
#define INDIM  32
#define HID    12
#define G4     48          // 4*HID
#define NB     (SEQ / 4)   // float4 blocks of 4 timesteps
#define NBLK   (NB + 4)    // zx blocks incl pad blocks
#define CHUNK  16
#define NCH    (SEQ / CHUNK)

#define LOG2E 1.4426950408889634f

typedef float f32x4 __attribute__((ext_vector_type(4)));

// ---- low-latency cross-lane primitives ------------------------------------
template<int CTRL>
__device__ __forceinline__ float qbcast(float v) {
    int x = __builtin_amdgcn_update_dpp(
        0, __builtin_bit_cast(int, v), CTRL, 0xF, 0xF, true);
    return __builtin_bit_cast(float, x);
}
__device__ __forceinline__ float lanebcast(float v, int lane) {
    return __builtin_bit_cast(float,
        __builtin_amdgcn_readlane(__builtin_bit_cast(int, v), lane));
}
__device__ __forceinline__ float sig_part(float zs) {   // rcp(1 + exp2(zs))
    return __builtin_amdgcn_rcpf(1.0f + __builtin_amdgcn_exp2f(zs));
}

// 12-FMA dot, 6 accumulators: depth = 2 fma + 3 add.
#define DOT12(acc_init, W, H, OUT) { \
    float d0 = (acc_init), d1 = 0.f, d2 = 0.f, d3 = 0.f, d4 = 0.f, d5 = 0.f; \
    d0 = fmaf(H[0], W[0], d0); d1 = fmaf(H[1],  W[1],  d1); d2 = fmaf(H[2],  W[2],  d2); \
    d3 = fmaf(H[3], W[3], d3); d4 = fmaf(H[4],  W[4],  d4); d5 = fmaf(H[5],  W[5],  d5); \
    d0 = fmaf(H[6], W[6], d0); d1 = fmaf(H[7],  W[7],  d1); d2 = fmaf(H[8],  W[8],  d2); \
    d3 = fmaf(H[9], W[9], d3); d4 = fmaf(H[10], W[10], d4); d5 = fmaf(H[11], W[11], d5); \
    OUT = ((d0 + d1) + (d2 + d3)) + (d4 + d5); \
}

// ---------------------------------------------------------------------------
// Kernel 1: layer-0 x-part, bias folded, PRE-SCALED by cexp(g):
//   zx[b*192 + j*4 + q] = cexp(g) * (b[r] + Wih0[r,:]·X[t,2047,:]),
//   t = 4b+q, j = 4*k+g, r = g*12+k.  Blocks b in [0,NBLK); t>=SEQ zeroed.
// ---------------------------------------------------------------------------
__global__ __launch_bounds__(256) void lstm_pre(
    const float* __restrict__ X,
    const float* __restrict__ Wih0,
    const float* __restrict__ bih0,
    const float* __restrict__ bhh0,
    float* __restrict__ zx)
{
    int idx = blockIdx.x * blockDim.x + threadIdx.x;
    if (idx >= NBLK * 192) return;
    int b   = idx / 192;
    int rem = idx - b * 192;
    int j   = rem >> 2;
    int q   = rem & 3;
    int t   = 4 * b + q;
    if (t >= SEQ) { zx[idx] = 0.0f; return; }
    int g = j & 3, k = j >> 2;
    int r = g * HID + k;
    const float cexpg = (g == 2) ? (-2.0f * LOG2E) : (-LOG2E);
    const float* x = X + (size_t)t * NBATCH * INDIM + (size_t)(NBATCH - 1) * INDIM;
    const float* w = Wih0 + r * INDIM;
    float za = bih0[r] + bhh0[r], zb = 0.0f;
    #pragma unroll
    for (int kk = 0; kk < INDIM; kk += 2) {
        za = fmaf(w[kk],     x[kk],     za);
        zb = fmaf(w[kk + 1], x[kk + 1], zb);
    }
    zx[idx] = (za + zb) * cexpg;
}

// ---------------------------------------------------------------------------
// Kernel 2: two-wave barrier-lockstep pipeline (best-measured structure).
// Wave A (layer 0): scalar-SGPR matvec for its z; also computes
//   y(t) = cexp*(b1 + Wih1·h0(t)) off-chain and writes it to a 64-step
//   LDS ring. Wave B (layer 1): one LDS y read/step (prefetched 4 ahead)
//   + 12-FMA dot + nonlinearity; h1 -> hbuf. Barrier per 16-step chunk,
//   B lags 2 chunks.
// ---------------------------------------------------------------------------
__global__ __launch_bounds__(128) void lstm_seq3(
    const f32x4* __restrict__ zx4,     // [NBLK][48] f32x4, pre-scaled
    float* __restrict__ hbuf,          // [SEQ][12] h1 per step
    const float* __restrict__ Whh0,
    const float* __restrict__ Wih1,
    const float* __restrict__ Whh1,
    const float* __restrict__ bih1,
    const float* __restrict__ bhh1)
{
    __shared__ float ylds[64 * 64];    // 64-step ring x 64 cols (48 used)

    const int tid  = threadIdx.x;
    const int wavei = tid >> 6;
    const int lane = tid & 63;
    const int jj = (lane < G4) ? lane : 0;
    const int g  = jj & 3;                 // gate: 0=i 1=f 2=g 3=o
    const int k  = jj >> 2;                // hidden unit
    const int r  = g * HID + k;            // weight row
    const float cexp = (g == 2) ? (-2.0f * LOG2E) : (-LOG2E);
    const float TSA = -4.0f * LOG2E;
    const float TSB =  2.0f * LOG2E;

    float wh0a[HID], wi1a[HID];      // A weights (scaled)
    float h0s[HID];  float cs0 = 0.f;
    f32x4 zbE[4], zbO[4];
    float b1s = 0.f;
    float wh1b[HID];                 // B weights (scaled)
    float h1s[HID];  float cs1 = 0.f;
    float yv0 = 0.f, yv1 = 0.f, yv2 = 0.f, yv3 = 0.f;

    if (wavei == 0) {
        #pragma unroll
        for (int kk = 0; kk < HID; ++kk) {
            wh0a[kk] = Whh0[r * HID + kk] * cexp;
            wi1a[kk] = Wih1[r * HID + kk] * cexp;
            h0s[kk] = 0.f;
        }
        b1s = (bih1[r] + bhh1[r]) * cexp;
        #pragma unroll
        for (int bb = 0; bb < 4; ++bb) zbE[bb] = zx4[bb * G4 + jj];
    } else {
        #pragma unroll
        for (int kk = 0; kk < HID; ++kk) {
            wh1b[kk] = Whh1[r * HID + kk] * cexp;
            h1s[kk] = 0.f;
        }
    }
    __syncthreads();

// gate combine: m1,m2 parallel depth-1, igs depth-2, cs depth-3 from rr
#define GATECOMB(rr, cs) { \
    float ai = qbcast<0x00>(rr), af = qbcast<0x55>(rr); \
    float ag = qbcast<0xAA>(rr); \
    float m1 = ai * ag; \
    float m2 = TSB * ai; \
    cs = fmaf(af, cs, fmaf(TSA, m1, m2)); \
}

#define STEPA(zs, t) { \
    float z0v; DOT12((zs), wh0a, h0s, z0v) \
    float rr = sig_part(z0v); \
    float ao = qbcast<0xFF>(rr); \
    GATECOMB(rr, cs0) \
    float rt = sig_part(cs0); \
    float h0 = fmaf(ao + ao, rt, -ao); \
    h0s[0] = lanebcast(h0, 0);  h0s[1] = lanebcast(h0, 4);  h0s[2]  = lanebcast(h0, 8); \
    h0s[3] = lanebcast(h0, 12); h0s[4] = lanebcast(h0, 16); h0s[5]  = lanebcast(h0, 20); \
    h0s[6] = lanebcast(h0, 24); h0s[7] = lanebcast(h0, 28); h0s[8]  = lanebcast(h0, 32); \
    h0s[9] = lanebcast(h0, 36); h0s[10] = lanebcast(h0, 40); h0s[11] = lanebcast(h0, 44); \
    float yo; DOT12(b1s, wi1a, h0s, yo) \
    ylds[(((t) & 63) << 6) + lane] = yo; \
}

#define AITER(cur, nxt, ci) { \
    int cb = 4 * ((ci) + 1); \
    nxt[0] = zx4[(cb + 0) * G4 + jj]; \
    nxt[1] = zx4[(cb + 1) * G4 + jj]; \
    nxt[2] = zx4[(cb + 2) * G4 + jj]; \
    nxt[3] = zx4[(cb + 3) * G4 + jj]; \
    int tA = CHUNK * (ci); \
    STEPA(cur[0].x, tA + 0)  STEPA(cur[0].y, tA + 1)  STEPA(cur[0].z, tA + 2)  STEPA(cur[0].w, tA + 3)  \
    STEPA(cur[1].x, tA + 4)  STEPA(cur[1].y, tA + 5)  STEPA(cur[1].z, tA + 6)  STEPA(cur[1].w, tA + 7)  \
    STEPA(cur[2].x, tA + 8)  STEPA(cur[2].y, tA + 9)  STEPA(cur[2].z, tA + 10) STEPA(cur[2].w, tA + 11) \
    STEPA(cur[3].x, tA + 12) STEPA(cur[3].y, tA + 13) STEPA(cur[3].z, tA + 14) STEPA(cur[3].w, tA + 15) \
}

#define STEPB(yin, t) { \
    float z1v; DOT12((yin), wh1b, h1s, z1v) \
    float rr = sig_part(z1v); \
    float ao = qbcast<0xFF>(rr); \
    GATECOMB(rr, cs1) \
    float rt = sig_part(cs1); \
    float h1 = fmaf(ao + ao, rt, -ao); \
    if (lane < G4 && g == 0) hbuf[(t) * HID + k] = h1; \
    h1s[0] = lanebcast(h1, 0);  h1s[1] = lanebcast(h1, 4);  h1s[2]  = lanebcast(h1, 8); \
    h1s[3] = lanebcast(h1, 12); h1s[4] = lanebcast(h1, 16); h1s[5]  = lanebcast(h1, 20); \
    h1s[6] = lanebcast(h1, 24); h1s[7] = lanebcast(h1, 28); h1s[8]  = lanebcast(h1, 32); \
    h1s[9] = lanebcast(h1, 36); h1s[10] = lanebcast(h1, 40); h1s[11] = lanebcast(h1, 44); \
}

#define BGRP(t0) { \
    int rb = ((((t0) + 4) & 63) << 6) + jj; \
    float n0 = ylds[rb], n1 = ylds[rb + 64], n2 = ylds[rb + 128], n3 = ylds[rb + 192]; \
    STEPB(yv0, (t0))     STEPB(yv1, (t0) + 1) \
    STEPB(yv2, (t0) + 2) STEPB(yv3, (t0) + 3) \
    yv0 = n0; yv1 = n1; yv2 = n2; yv3 = n3; \
}

    for (int i = 0; i < NCH + 2; ++i) {
        if (wavei == 0) {
            if (i < NCH) {
                if ((i & 1) == 0) { AITER(zbE, zbO, i) }
                else              { AITER(zbO, zbE, i) }
            }
        } else {
            if (i >= 2) {
                int t0 = (i - 2) * CHUNK;
                if (i == 2) {
                    yv0 = ylds[jj];       yv1 = ylds[64 + jj];
                    yv2 = ylds[128 + jj]; yv3 = ylds[192 + jj];
                }
                BGRP(t0) BGRP(t0 + 4) BGRP(t0 + 8) BGRP(t0 + 12)
            }
        }
        __syncthreads();
    }
#undef STEPA
#undef AITER
#undef STEPB
#undef BGRP
#undef GATECOMB
}

// ---------------------------------------------------------------------------
// Kernel 3: FC head, parallel over t: out[t] = bfc + Wfc . h1(t)
// ---------------------------------------------------------------------------
__global__ __launch_bounds__(256) void fc_head(
    const float* __restrict__ hbuf,
    const float* __restrict__ Wfc,
    const float* __restrict__ bfc,
    float* __restrict__ out)
{
    int t = blockIdx.x * blockDim.x + threadIdx.x;
    if (t >= SEQ) return;
    float o = bfc[0];
    const float* h = hbuf + t * HID;
    #pragma unroll
    for (int kk = 0; kk < HID; ++kk) o = fmaf(Wfc[kk], h[kk], o);
    out[t] = o;
}

// ---------------------------------------------------------------------------
// Fallback (no workspace): single-wave full computation, inline FC.
// ---------------------------------------------------------------------------
__global__ __launch_bounds__(64) void lstm_seq_fb(
    const float* __restrict__ X,
    const float* __restrict__ Wih0,
    const float* __restrict__ bih0,
    const float* __restrict__ bhh0,
    const float* __restrict__ Whh0,
    const float* __restrict__ Wih1,
    const float* __restrict__ Whh1,
    const float* __restrict__ bih1,
    const float* __restrict__ bhh1,
    const float* __restrict__ Wfc,
    const float* __restrict__ bfc,
    float* __restrict__ out)
{
    const int j  = threadIdx.x;
    const int jj = (j < G4) ? j : 0;
    const int g  = jj & 3;
    const int k  = jj >> 2;
    const int r  = g * HID + k;
    const float cexp = (g == 2) ? (-2.0f * LOG2E) : (-LOG2E);
    const float TSA = -4.0f * LOG2E;
    const float TSB =  2.0f * LOG2E;

    float whh0[HID], wih1[HID], whh1[HID], wih0[INDIM], wfc[HID];
    #pragma unroll
    for (int kk = 0; kk < HID; ++kk) {
        whh0[kk] = Whh0[r * HID + kk] * cexp;
        wih1[kk] = Wih1[r * HID + kk] * cexp;
        whh1[kk] = Whh1[r * HID + kk] * cexp;
        wfc[kk]  = Wfc[kk];
    }
    #pragma unroll
    for (int kk = 0; kk < INDIM; ++kk) wih0[kk] = Wih0[r * INDIM + kk] * cexp;
    const float b0 = (bih0[r] + bhh0[r]) * cexp;
    const float b1 = (bih1[r] + bhh1[r]) * cexp;
    const float bias_fc = bfc[0];

    float h0v[HID], h1v[HID];
    #pragma unroll
    for (int kk = 0; kk < HID; ++kk) { h0v[kk] = 0.0f; h1v[kk] = 0.0f; }
    float cs0 = 0.0f, cs1 = 0.0f;

    for (int t = 0; t < SEQ; ++t) {
        const float* x = X + (size_t)t * NBATCH * INDIM
                           + (size_t)(NBATCH - 1) * INDIM;
        float z0 = b0;
        #pragma unroll
        for (int kk = 0; kk < INDIM; ++kk) z0 = fmaf(wih0[kk], x[kk], z0);
        #pragma unroll
        for (int kk = 0; kk < HID; ++kk) z0 = fmaf(whh0[kk], h0v[kk], z0);
        float rr = sig_part(z0);
        float ai = qbcast<0x00>(rr), af = qbcast<0x55>(rr);
        float ag = qbcast<0xAA>(rr), ao = qbcast<0xFF>(rr);
        cs0 = fmaf(af, cs0, ai * fmaf(TSA, ag, TSB));
        float rt = sig_part(cs0);
        float h0 = fmaf(ao + ao, rt, -ao);
        #pragma unroll
        for (int kk = 0; kk < HID; ++kk) h0v[kk] = lanebcast(h0, 4 * kk);

        float z1 = b1;
        #pragma unroll
        for (int kk = 0; kk < HID; ++kk) {
            z1 = fmaf(wih1[kk], h0v[kk], z1);
            z1 = fmaf(whh1[kk], h1v[kk], z1);
        }
        rr = sig_part(z1);
        ai = qbcast<0x00>(rr); af = qbcast<0x55>(rr);
        ag = qbcast<0xAA>(rr); ao = qbcast<0xFF>(rr);
        cs1 = fmaf(af, cs1, ai * fmaf(TSA, ag, TSB));
        rt = sig_part(cs1);
        float h1 = fmaf(ao + ao, rt, -ao);
        #pragma unroll
        for (int kk = 0; kk < HID; ++kk) h1v[kk] = lanebcast(h1, 4 * kk);

        float o = bias_fc;
        #pragma unroll
        for (int kk = 0; kk < HID; ++kk) o = fmaf(wfc[kk], h1v[kk], o);
        if (j == 0) out[t] = o;
    }
}

extern "C" void kernel_launch(void* const* d_in, const int* in_sizes, int n_in,
                              void* d_out, int out_size, void* d_ws, size_t ws_size,
                              hipStream_t stream) {
    const float* X    = (const float*)d_in[0];
    const float* Wih0 = (const float*)d_in[1];
    const float* Whh0 = (const float*)d_in[2];
    const float* bih0 = (const float*)d_in[3];
    const float* bhh0 = (const float*)d_in[4];
    const float* Wih1 = (const float*)d_in[5];
    const float* Whh1 = (const float*)d_in[6];
    const float* bih1 = (const float*)d_in[7];
    const float* bhh1 = (const float*)d_in[8];
    const float* Wfc  = (const float*)d_in[9];
    const float* bfc  = (const float*)d_in[10];
    float* out = (float*)d_out;

    const size_t zx_floats = (size_t)NBLK * 192;
    const size_t need = (zx_floats + (size_t)SEQ * HID) * sizeof(float);
    if (ws_size >= need) {
        float* zbuf = (float*)d_ws;
        float* hbuf = zbuf + zx_floats;
        lstm_pre<<<(NBLK * 192 + 255) / 256, 256, 0, stream>>>(
            X, Wih0, bih0, bhh0, zbuf);
        lstm_seq3<<<1, 128, 0, stream>>>(
            (const f32x4*)zbuf, hbuf, Whh0, Wih1, Whh1, bih1, bhh1);
        fc_head<<<(SEQ + 255) / 256, 256, 0, stream>>>(hbuf, Wfc, bfc, out);
    } else {
        lstm_seq_fb<<<1, 64, 0, stream>>>(
            X, Wih0, bih0, bhh0, Whh0,
            Wih1, Whh1, bih1, bhh1, Wfc, bfc, out);
    }
}